// Round 2
// baseline (159.033 us; speedup 1.0000x reference)
//
#include <hip/hip_runtime.h>
#include <math.h>

#define CCH 512      // channels
#define FH 76        // feature H
#define FW 128       // feature W
#define NP 256       // proposals
#define HID 200      // hidden width
#define NKC 16       // K-chunks for layer1 split-K
#define L1_KC 128    // K per chunk
#define L1_ROWS 8    // proposals per l1 block

// ---------------- Kernel 1: ROI adaptive 2x2 max-pool ----------------
// One block per proposal; 512 threads = 4 bins (wave-uniform t>>7) x 128
// float4 channel-groups. float4 loads: 16B/lane, fully coalesced.
__global__ __launch_bounds__(512) void pool_kernel(
    const float4* __restrict__ fm4, const int* __restrict__ coords,
    float4* __restrict__ f4)
{
    const int n  = blockIdx.x;
    const int t  = threadIdx.x;
    const int bin = t >> 7;          // uniform within each wave
    const int by = bin >> 1, bx = bin & 1;
    const int cg = t & 127;          // float4 group: channels 4*cg..4*cg+3
    const int c0 = coords[n*4+0], c1 = coords[n*4+1];
    const int c2 = coords[n*4+2], c3 = coords[n*4+3];
    const int sy = min(c0 >> 3, FH - 2);
    const int sx = min(c1 >> 3, FW - 2);
    const int h = max(((c2 + 7) >> 3) - sy, 2);
    const int w = max(((c3 + 7) >> 3) - sx, 2);
    // adaptive bin i covers [i*size/2, ((i+1)*size+1)/2)
    const int rs = by ? (h >> 1) : 0;
    const int re = by ? h : ((h + 1) >> 1);
    const int cs = bx ? (w >> 1) : 0;
    const int ce = bx ? w : ((w + 1) >> 1);
    float4 m = make_float4(-1e30f, -1e30f, -1e30f, -1e30f);
    for (int r = rs; r < re; ++r) {
        const float4* row = fm4 + ((size_t)(sy + r) * FW + sx + cs) * (CCH/4) + cg;
        for (int cc = 0; cc < ce - cs; ++cc) {
            const float4 v = row[(size_t)cc * (CCH/4)];
            m.x = fmaxf(m.x, v.x); m.y = fmaxf(m.y, v.y);
            m.z = fmaxf(m.z, v.z); m.w = fmaxf(m.w, v.w);
        }
    }
    f4[(size_t)n * (4*CCH/4) + bin * (CCH/4) + cg] = m;
}

// ---------------- Kernel 2: layer1 split-K GEMM, partials (no atomics) ---
// part[kc][n][j] = sum_{k in chunk kc} f[n][k] * W1[k][j]
// grid (32 row-tiles, 16 k-chunks), block 256 (thread j = output column).
__global__ __launch_bounds__(256) void l1_kernel(
    const float* __restrict__ f, const float* __restrict__ W1,
    float* __restrict__ part)
{
    const int j = threadIdx.x;
    if (j >= HID) return;
    const int r0 = blockIdx.x * L1_ROWS;
    const int kc = blockIdx.y;
    const int k0 = kc * L1_KC;
    float acc[L1_ROWS];
    #pragma unroll
    for (int r = 0; r < L1_ROWS; ++r) acc[r] = 0.0f;
    const float* fp = f  + (size_t)r0 * 2048 + k0;   // wave-uniform -> s_load path
    const float* wp = W1 + (size_t)k0 * HID + j;     // coalesced across j
    #pragma unroll 4
    for (int k = 0; k < L1_KC; ++k) {
        const float wv = wp[(size_t)k * HID];
        #pragma unroll
        for (int r = 0; r < L1_ROWS; ++r)
            acc[r] += fp[(size_t)r * 2048 + k] * wv;
    }
    float* pp = part + ((size_t)kc * NP + r0) * HID + j;
    #pragma unroll
    for (int r = 0; r < L1_ROWS; ++r)
        pp[(size_t)r * HID] = acc[r];
}

// ---------------- Kernel 3: reduce + layer2 + heads + postprocess --------
// One block per proposal.
__global__ __launch_bounds__(256) void head_kernel(
    const float* __restrict__ part,
    const float* __restrict__ b1, const float* __restrict__ W2,
    const float* __restrict__ b2, const float* __restrict__ W3,
    const float* __restrict__ b3, const float* __restrict__ W4,
    const float* __restrict__ b4, const int* __restrict__ coords,
    float* __restrict__ out)
{
    __shared__ float h1s[HID];
    __shared__ float h2s[HID];
    __shared__ float hd[21];     // 16 reg + 5 cls
    const int n = blockIdx.x;
    const int t = threadIdx.x;
    if (t < HID) {
        float a = b1[t];
        #pragma unroll
        for (int c = 0; c < NKC; ++c)
            a += part[((size_t)c * NP + n) * HID + t];
        h1s[t] = fmaxf(a, 0.0f);
    }
    __syncthreads();
    if (t < HID) {
        float acc = b2[t];
        #pragma unroll 8
        for (int k = 0; k < HID; ++k)
            acc += h1s[k] * W2[k * HID + t];
        h2s[t] = fmaxf(acc, 0.0f);
    }
    __syncthreads();
    if (t < 21) {
        float acc;
        if (t < 16) {
            acc = b3[t];
            #pragma unroll 8
            for (int k = 0; k < HID; ++k) acc += h2s[k] * W3[k * 16 + t];
        } else {
            const int ci = t - 16;
            acc = b4[ci];
            #pragma unroll 8
            for (int k = 0; k < HID; ++k) acc += h2s[k] * W4[k * 5 + ci];
        }
        hd[t] = acc;
    }
    __syncthreads();
    if (t == 0) {
        const float cv0 = hd[16], cv1 = hd[17], cv2 = hd[18],
                    cv3 = hd[19], cv4 = hd[20];
        // jnp.argmax: first occurrence of max -> strict '>'
        int cls = 0; float best = cv0;
        if (cv1 > best) { best = cv1; cls = 1; }
        if (cv2 > best) { best = cv2; cls = 2; }
        if (cv3 > best) { best = cv3; cls = 3; }
        if (cv4 > best) { best = cv4; cls = 4; }
        const float e0 = expf(cv0 - best), e1 = expf(cv1 - best),
                    e2 = expf(cv2 - best), e3 = expf(cv3 - best),
                    e4 = expf(cv4 - best);
        const float s = e0 + e1 + e2 + e3 + e4;
        const float score = fmaxf(fmaxf(e1, e2), fmaxf(e3, e4)) / s;
        const int ri = max(cls - 1, 0);
        const float rg0 = hd[ri*4+0], rg1 = hd[ri*4+1],
                    rg2 = hd[ri*4+2], rg3 = hd[ri*4+3];
        const float y0 = (float)coords[n*4+0], x0 = (float)coords[n*4+1];
        const float y1 = (float)coords[n*4+2], x1 = (float)coords[n*4+3];
        const float ph = y1 - y0, pw = x1 - x0;
        const float py = y0 + 0.5f * ph, px = x0 + 0.5f * pw;
        const float oy = ph * rg0 + py;
        const float ox = pw * rg1 + px;
        const float oh = ph * fminf(fmaxf(expf(rg2), 0.001f), 20.0f);
        const float ow = pw * fminf(fmaxf(expf(rg3), 0.001f), 20.0f);
        out[n*4+0] = oy; out[n*4+1] = ox; out[n*4+2] = oh; out[n*4+3] = ow;
        out[NP*4 + n] = score;                       // scores block
        out[NP*5 + n] = (cls != 0) ? 1.0f : 0.0f;    // mask block (bool as fp32)
    }
}

extern "C" void kernel_launch(void* const* d_in, const int* in_sizes, int n_in,
                              void* d_out, int out_size, void* d_ws, size_t ws_size,
                              hipStream_t stream) {
    const float* fm     = (const float*)d_in[0];   // [1,76,128,512]
    const int*   coords = (const int*)  d_in[1];   // [256,4]
    const float* W1 = (const float*)d_in[2];       // [2048,200]
    const float* b1 = (const float*)d_in[3];
    const float* W2 = (const float*)d_in[4];       // [200,200]
    const float* b2 = (const float*)d_in[5];
    const float* W3 = (const float*)d_in[6];       // [200,16]
    const float* b3 = (const float*)d_in[7];
    const float* W4 = (const float*)d_in[8];       // [200,5]
    const float* b4 = (const float*)d_in[9];
    float* out = (float*)d_out;                    // 1024 boxes + 256 scores + 256 mask

    float* f    = (float*)d_ws;                    // [256, 2048]
    float* part = f + (size_t)NP * 2048;           // [16, 256, 200]

    pool_kernel<<<NP, 512, 0, stream>>>((const float4*)fm, coords, (float4*)f);
    l1_kernel  <<<dim3(NP / L1_ROWS, NKC), 256, 0, stream>>>(f, W1, part);
    head_kernel<<<NP, 256, 0, stream>>>(part, b1, W2, b2, W3, b3, W4, b4,
                                        coords, out);
}

// Round 3
// 134.646 us; speedup vs baseline: 1.1811x; 1.1811x over previous
//
#include <hip/hip_runtime.h>
#include <math.h>

#define CCH 512      // channels
#define FH 76        // feature H
#define FW 128       // feature W
#define NP 256       // proposals
#define HID 200      // hidden width
#define NKC 16       // K-chunks for layer1 split-K
#define L1_KC 128    // K per chunk
#define L1_ROWS 8    // proposals per l1 block

// ---------------- Kernel 1: ROI adaptive 2x2 max-pool ----------------
// grid (256 proposals, 4 bins) = 1024 blocks (32 waves/CU), block 512 =
// 4 row-slots x 128 float4 channel-groups. Inner col loop unrolled 4x so
// 4 independent 16B loads are in flight per wait. LDS reduce over row-slots.
__global__ __launch_bounds__(512) void pool_kernel(
    const float4* __restrict__ fm4, const int* __restrict__ coords,
    float4* __restrict__ f4)
{
    __shared__ float4 smem[4][128];
    const int n   = blockIdx.x;
    const int bin = blockIdx.y;
    const int by = bin >> 1, bx = bin & 1;
    const int t  = threadIdx.x;
    const int rslot = t >> 7;        // 0..3
    const int cg    = t & 127;       // float4 group: channels 4*cg..4*cg+3
    const int c0 = coords[n*4+0], c1 = coords[n*4+1];
    const int c2 = coords[n*4+2], c3 = coords[n*4+3];
    const int sy = min(c0 >> 3, FH - 2);
    const int sx = min(c1 >> 3, FW - 2);
    const int h = max(((c2 + 7) >> 3) - sy, 2);
    const int w = max(((c3 + 7) >> 3) - sx, 2);
    // adaptive bin i covers [i*size/2, ((i+1)*size+1)/2)
    const int rs = by ? (h >> 1) : 0;
    const int re = by ? h : ((h + 1) >> 1);
    const int cs = bx ? (w >> 1) : 0;
    const int ce = bx ? w : ((w + 1) >> 1);
    const int nc = ce - cs;          // 1..12 cols in this bin
    float4 m = make_float4(-1e30f, -1e30f, -1e30f, -1e30f);
    for (int r = rs + rslot; r < re; r += 4) {
        const float4* row = fm4 + ((size_t)(sy + r) * FW + sx + cs) * (CCH/4) + cg;
        #pragma unroll 4
        for (int cc = 0; cc < nc; ++cc) {
            const float4 v = row[(size_t)cc * (CCH/4)];
            m.x = fmaxf(m.x, v.x); m.y = fmaxf(m.y, v.y);
            m.z = fmaxf(m.z, v.z); m.w = fmaxf(m.w, v.w);
        }
    }
    smem[rslot][cg] = m;
    __syncthreads();
    if (t < 128) {
        float4 a = smem[0][t], b = smem[1][t];
        float4 c = smem[2][t], d = smem[3][t];
        float4 o;
        o.x = fmaxf(fmaxf(a.x, b.x), fmaxf(c.x, d.x));
        o.y = fmaxf(fmaxf(a.y, b.y), fmaxf(c.y, d.y));
        o.z = fmaxf(fmaxf(a.z, b.z), fmaxf(c.z, d.z));
        o.w = fmaxf(fmaxf(a.w, b.w), fmaxf(c.w, d.w));
        f4[(size_t)n * (4*CCH/4) + bin * (CCH/4) + t] = o;
    }
}

// ---------------- Kernel 2: layer1 split-K GEMM, partials (no atomics) ---
// part[kc][n][j] = sum_{k in chunk kc} f[n][k] * W1[k][j]
// grid (32 row-tiles, 16 k-chunks), block 256 (thread j = output column).
__global__ __launch_bounds__(256) void l1_kernel(
    const float* __restrict__ f, const float* __restrict__ W1,
    float* __restrict__ part)
{
    const int j = threadIdx.x;
    if (j >= HID) return;
    const int r0 = blockIdx.x * L1_ROWS;
    const int kc = blockIdx.y;
    const int k0 = kc * L1_KC;
    float acc[L1_ROWS];
    #pragma unroll
    for (int r = 0; r < L1_ROWS; ++r) acc[r] = 0.0f;
    const float* fp = f  + (size_t)r0 * 2048 + k0;   // wave-uniform -> s_load path
    const float* wp = W1 + (size_t)k0 * HID + j;     // coalesced across j
    #pragma unroll 4
    for (int k = 0; k < L1_KC; ++k) {
        const float wv = wp[(size_t)k * HID];
        #pragma unroll
        for (int r = 0; r < L1_ROWS; ++r)
            acc[r] += fp[(size_t)r * 2048 + k] * wv;
    }
    float* pp = part + ((size_t)kc * NP + r0) * HID + j;
    #pragma unroll
    for (int r = 0; r < L1_ROWS; ++r)
        pp[(size_t)r * HID] = acc[r];
}

// ---------------- Kernel 3: reduce + layer2 + heads + postprocess --------
// One block per proposal.
__global__ __launch_bounds__(256) void head_kernel(
    const float* __restrict__ part,
    const float* __restrict__ b1, const float* __restrict__ W2,
    const float* __restrict__ b2, const float* __restrict__ W3,
    const float* __restrict__ b3, const float* __restrict__ W4,
    const float* __restrict__ b4, const int* __restrict__ coords,
    float* __restrict__ out)
{
    __shared__ float h1s[HID];
    __shared__ float h2s[HID];
    __shared__ float hd[21];     // 16 reg + 5 cls
    const int n = blockIdx.x;
    const int t = threadIdx.x;
    if (t < HID) {
        float a = b1[t];
        #pragma unroll
        for (int c = 0; c < NKC; ++c)
            a += part[((size_t)c * NP + n) * HID + t];
        h1s[t] = fmaxf(a, 0.0f);
    }
    __syncthreads();
    if (t < HID) {
        float acc = b2[t];
        #pragma unroll 8
        for (int k = 0; k < HID; ++k)
            acc += h1s[k] * W2[k * HID + t];
        h2s[t] = fmaxf(acc, 0.0f);
    }
    __syncthreads();
    if (t < 21) {
        float acc;
        if (t < 16) {
            acc = b3[t];
            #pragma unroll 8
            for (int k = 0; k < HID; ++k) acc += h2s[k] * W3[k * 16 + t];
        } else {
            const int ci = t - 16;
            acc = b4[ci];
            #pragma unroll 8
            for (int k = 0; k < HID; ++k) acc += h2s[k] * W4[k * 5 + ci];
        }
        hd[t] = acc;
    }
    __syncthreads();
    if (t == 0) {
        const float cv0 = hd[16], cv1 = hd[17], cv2 = hd[18],
                    cv3 = hd[19], cv4 = hd[20];
        // jnp.argmax: first occurrence of max -> strict '>'
        int cls = 0; float best = cv0;
        if (cv1 > best) { best = cv1; cls = 1; }
        if (cv2 > best) { best = cv2; cls = 2; }
        if (cv3 > best) { best = cv3; cls = 3; }
        if (cv4 > best) { best = cv4; cls = 4; }
        const float e0 = expf(cv0 - best), e1 = expf(cv1 - best),
                    e2 = expf(cv2 - best), e3 = expf(cv3 - best),
                    e4 = expf(cv4 - best);
        const float s = e0 + e1 + e2 + e3 + e4;
        const float score = fmaxf(fmaxf(e1, e2), fmaxf(e3, e4)) / s;
        const int ri = max(cls - 1, 0);
        const float rg0 = hd[ri*4+0], rg1 = hd[ri*4+1],
                    rg2 = hd[ri*4+2], rg3 = hd[ri*4+3];
        const float y0 = (float)coords[n*4+0], x0 = (float)coords[n*4+1];
        const float y1 = (float)coords[n*4+2], x1 = (float)coords[n*4+3];
        const float ph = y1 - y0, pw = x1 - x0;
        const float py = y0 + 0.5f * ph, px = x0 + 0.5f * pw;
        const float oy = ph * rg0 + py;
        const float ox = pw * rg1 + px;
        const float oh = ph * fminf(fmaxf(expf(rg2), 0.001f), 20.0f);
        const float ow = pw * fminf(fmaxf(expf(rg3), 0.001f), 20.0f);
        out[n*4+0] = oy; out[n*4+1] = ox; out[n*4+2] = oh; out[n*4+3] = ow;
        out[NP*4 + n] = score;                       // scores block
        out[NP*5 + n] = (cls != 0) ? 1.0f : 0.0f;    // mask block (bool as fp32)
    }
}

extern "C" void kernel_launch(void* const* d_in, const int* in_sizes, int n_in,
                              void* d_out, int out_size, void* d_ws, size_t ws_size,
                              hipStream_t stream) {
    const float* fm     = (const float*)d_in[0];   // [1,76,128,512]
    const int*   coords = (const int*)  d_in[1];   // [256,4]
    const float* W1 = (const float*)d_in[2];       // [2048,200]
    const float* b1 = (const float*)d_in[3];
    const float* W2 = (const float*)d_in[4];       // [200,200]
    const float* b2 = (const float*)d_in[5];
    const float* W3 = (const float*)d_in[6];       // [200,16]
    const float* b3 = (const float*)d_in[7];
    const float* W4 = (const float*)d_in[8];       // [200,5]
    const float* b4 = (const float*)d_in[9];
    float* out = (float*)d_out;                    // 1024 boxes + 256 scores + 256 mask

    float* f    = (float*)d_ws;                    // [256, 2048]
    float* part = f + (size_t)NP * 2048;           // [16, 256, 200]

    pool_kernel<<<dim3(NP, 4), 512, 0, stream>>>((const float4*)fm, coords,
                                                 (float4*)f);
    l1_kernel  <<<dim3(NP / L1_ROWS, NKC), 256, 0, stream>>>(f, W1, part);
    head_kernel<<<NP, 256, 0, stream>>>(part, b1, W2, b2, W3, b3, W4, b4,
                                        coords, out);
}

// Round 4
// 127.763 us; speedup vs baseline: 1.2447x; 1.0539x over previous
//
#include <hip/hip_runtime.h>
#include <math.h>

#define CCH 512      // channels
#define FH 76        // feature H
#define FW 128       // feature W
#define NP 256       // proposals
#define HID 200      // hidden width
#define NKC 16       // K-chunks for layer1 split-K
#define L1_KC 128    // K per chunk
#define L1_ROWS 8    // proposals per l1 block
#define FM4 (FH * FW * (CCH / 4))      // 1,245,184 float4 in feature map
#define POOL_THREADS (NP * 4 * 512)    // 524,288 threads in pool grid

// ---------------- Kernel 1: ROI adaptive 2x2 max-pool ----------------
// Phase A: cooperative coalesced stream of the whole feature map (fm is
// HBM-cold every iteration: the harness's 268MB ws poison cycles all of L3).
// Linear read warms L2/L3 at streaming BW so Phase B's scattered 2KB row
// reads hit cache instead of cold HBM (R2 profile: 33MB @ 0.79 TB/s).
// Phase B: grid (256 proposals, 4 bins), block 512 = 4 row-slots x 128
// float4 channel-groups, LDS reduce over row-slots.
__global__ __launch_bounds__(512) void pool_kernel(
    const float4* __restrict__ fm4, const int* __restrict__ coords,
    float4* __restrict__ f4, float* __restrict__ scratch)
{
    __shared__ float4 smem[4][128];
    const int n   = blockIdx.x;
    const int bin = blockIdx.y;
    const int t   = threadIdx.x;

    // ---- Phase A: warm read (3 coalesced float4 per thread) ----
    const int gtid = (blockIdx.y * NP + blockIdx.x) * 512 + t;
    float wacc = -1e30f;
    #pragma unroll
    for (int i = 0; i < 3; ++i) {
        const int idx = gtid + i * POOL_THREADS;
        if (idx < FM4) {
            const float4 v = fm4[idx];
            wacc = fmaxf(wacc, fmaxf(fmaxf(v.x, v.y), fmaxf(v.z, v.w)));
        }
    }

    // ---- Phase B: scattered ROI reads (overlap with A's in-flight loads) ----
    const int by = bin >> 1, bx = bin & 1;
    const int rslot = t >> 7;        // 0..3
    const int cg    = t & 127;       // float4 group: channels 4*cg..4*cg+3
    const int c0 = coords[n*4+0], c1 = coords[n*4+1];
    const int c2 = coords[n*4+2], c3 = coords[n*4+3];
    const int sy = min(c0 >> 3, FH - 2);
    const int sx = min(c1 >> 3, FW - 2);
    const int h = max(((c2 + 7) >> 3) - sy, 2);
    const int w = max(((c3 + 7) >> 3) - sx, 2);
    const int rs = by ? (h >> 1) : 0;
    const int re = by ? h : ((h + 1) >> 1);
    const int cs = bx ? (w >> 1) : 0;
    const int ce = bx ? w : ((w + 1) >> 1);
    const int nc = ce - cs;          // 1..12 cols in this bin
    float4 m = make_float4(-1e30f, -1e30f, -1e30f, -1e30f);
    for (int r = rs + rslot; r < re; r += 4) {
        const float4* row = fm4 + ((size_t)(sy + r) * FW + sx + cs) * (CCH/4) + cg;
        #pragma unroll 4
        for (int cc = 0; cc < nc; ++cc) {
            const float4 v = row[(size_t)cc * (CCH/4)];
            m.x = fmaxf(m.x, v.x); m.y = fmaxf(m.y, v.y);
            m.z = fmaxf(m.z, v.z); m.w = fmaxf(m.w, v.w);
        }
    }
    smem[rslot][cg] = m;
    __syncthreads();
    if (t < 128) {
        float4 a = smem[0][t], b = smem[1][t];
        float4 c = smem[2][t], d = smem[3][t];
        float4 o;
        o.x = fmaxf(fmaxf(a.x, b.x), fmaxf(c.x, d.x));
        o.y = fmaxf(fmaxf(a.y, b.y), fmaxf(c.y, d.y));
        o.z = fmaxf(fmaxf(a.z, b.z), fmaxf(c.z, d.z));
        o.w = fmaxf(fmaxf(a.w, b.w), fmaxf(c.w, d.w));
        f4[(size_t)n * (4*CCH/4) + bin * (CCH/4) + t] = o;
    }
    // DCE guard for Phase A: data-dependent, never true for N(0,1) inputs;
    // target is ws scratch, so even a freak hit is harmless.
    if (wacc == -1e30f && gtid == 0) scratch[0] = wacc;
}

// ---------------- Kernel 2: layer1 split-K GEMM, partials (no atomics) ---
// part[kc][n][j] = sum_{k in chunk kc} f[n][k] * W1[k][j]
// grid (32 row-tiles, 16 k-chunks), block 256 (thread j = output column).
__global__ __launch_bounds__(256) void l1_kernel(
    const float* __restrict__ f, const float* __restrict__ W1,
    float* __restrict__ part)
{
    const int j = threadIdx.x;
    if (j >= HID) return;
    const int r0 = blockIdx.x * L1_ROWS;
    const int kc = blockIdx.y;
    const int k0 = kc * L1_KC;
    float acc[L1_ROWS];
    #pragma unroll
    for (int r = 0; r < L1_ROWS; ++r) acc[r] = 0.0f;
    const float* fp = f  + (size_t)r0 * 2048 + k0;   // wave-uniform -> s_load path
    const float* wp = W1 + (size_t)k0 * HID + j;     // coalesced across j
    #pragma unroll 8
    for (int k = 0; k < L1_KC; ++k) {
        const float wv = wp[(size_t)k * HID];
        #pragma unroll
        for (int r = 0; r < L1_ROWS; ++r)
            acc[r] += fp[(size_t)r * 2048 + k] * wv;
    }
    float* pp = part + ((size_t)kc * NP + r0) * HID + j;
    #pragma unroll
    for (int r = 0; r < L1_ROWS; ++r)
        pp[(size_t)r * HID] = acc[r];
}

// ---------------- Kernel 3: reduce + layer2 + heads + postprocess --------
// One block (512 threads) per proposal; layer2 and heads are split over
// 2 K-halves (kc = t>>8, wave-uniform) to halve the serial load chains.
__global__ __launch_bounds__(512) void head_kernel(
    const float* __restrict__ part,
    const float* __restrict__ b1, const float* __restrict__ W2,
    const float* __restrict__ b2, const float* __restrict__ W3,
    const float* __restrict__ b3, const float* __restrict__ W4,
    const float* __restrict__ b4, const int* __restrict__ coords,
    float* __restrict__ out)
{
    __shared__ float h1s[HID];
    __shared__ float h2s[HID];
    __shared__ float p2[2][HID];
    __shared__ float hdp[2][21];
    __shared__ float hd[21];     // 16 reg + 5 cls
    const int n = blockIdx.x;
    const int t = threadIdx.x;
    const int kc = t >> 8;       // 0..1, wave-uniform
    const int j  = t & 255;
    if (t < HID) {
        float a = b1[t];
        #pragma unroll
        for (int c = 0; c < NKC; ++c)
            a += part[((size_t)c * NP + n) * HID + t];
        h1s[t] = fmaxf(a, 0.0f);
    }
    __syncthreads();
    if (j < HID) {
        const int k0 = kc * 100;
        float acc = 0.0f;
        #pragma unroll 10
        for (int k = 0; k < 100; ++k)
            acc += h1s[k0 + k] * W2[(k0 + k) * HID + j];
        p2[kc][j] = acc;
    }
    __syncthreads();
    if (t < HID) h2s[t] = fmaxf(p2[0][t] + p2[1][t] + b2[t], 0.0f);
    __syncthreads();
    if (j < 21) {
        const int k0 = kc * 100;
        float acc = 0.0f;
        if (j < 16) {
            #pragma unroll 5
            for (int k = 0; k < 100; ++k)
                acc += h2s[k0 + k] * W3[(k0 + k) * 16 + j];
        } else {
            const int ci = j - 16;
            #pragma unroll 5
            for (int k = 0; k < 100; ++k)
                acc += h2s[k0 + k] * W4[(k0 + k) * 5 + ci];
        }
        hdp[kc][j] = acc;
    }
    __syncthreads();
    if (t < 21)
        hd[t] = hdp[0][t] + hdp[1][t] + (t < 16 ? b3[t] : b4[t - 16]);
    __syncthreads();
    if (t == 0) {
        const float cv0 = hd[16], cv1 = hd[17], cv2 = hd[18],
                    cv3 = hd[19], cv4 = hd[20];
        // jnp.argmax: first occurrence of max -> strict '>'
        int cls = 0; float best = cv0;
        if (cv1 > best) { best = cv1; cls = 1; }
        if (cv2 > best) { best = cv2; cls = 2; }
        if (cv3 > best) { best = cv3; cls = 3; }
        if (cv4 > best) { best = cv4; cls = 4; }
        const float e0 = expf(cv0 - best), e1 = expf(cv1 - best),
                    e2 = expf(cv2 - best), e3 = expf(cv3 - best),
                    e4 = expf(cv4 - best);
        const float s = e0 + e1 + e2 + e3 + e4;
        const float score = fmaxf(fmaxf(e1, e2), fmaxf(e3, e4)) / s;
        const int ri = max(cls - 1, 0);
        const float rg0 = hd[ri*4+0], rg1 = hd[ri*4+1],
                    rg2 = hd[ri*4+2], rg3 = hd[ri*4+3];
        const float y0 = (float)coords[n*4+0], x0 = (float)coords[n*4+1];
        const float y1 = (float)coords[n*4+2], x1 = (float)coords[n*4+3];
        const float ph = y1 - y0, pw = x1 - x0;
        const float py = y0 + 0.5f * ph, px = x0 + 0.5f * pw;
        const float oy = ph * rg0 + py;
        const float ox = pw * rg1 + px;
        const float oh = ph * fminf(fmaxf(expf(rg2), 0.001f), 20.0f);
        const float ow = pw * fminf(fmaxf(expf(rg3), 0.001f), 20.0f);
        out[n*4+0] = oy; out[n*4+1] = ox; out[n*4+2] = oh; out[n*4+3] = ow;
        out[NP*4 + n] = score;                       // scores block
        out[NP*5 + n] = (cls != 0) ? 1.0f : 0.0f;    // mask block (bool as fp32)
    }
}

extern "C" void kernel_launch(void* const* d_in, const int* in_sizes, int n_in,
                              void* d_out, int out_size, void* d_ws, size_t ws_size,
                              hipStream_t stream) {
    const float* fm     = (const float*)d_in[0];   // [1,76,128,512]
    const int*   coords = (const int*)  d_in[1];   // [256,4]
    const float* W1 = (const float*)d_in[2];       // [2048,200]
    const float* b1 = (const float*)d_in[3];
    const float* W2 = (const float*)d_in[4];       // [200,200]
    const float* b2 = (const float*)d_in[5];
    const float* W3 = (const float*)d_in[6];       // [200,16]
    const float* b3 = (const float*)d_in[7];
    const float* W4 = (const float*)d_in[8];       // [200,5]
    const float* b4 = (const float*)d_in[9];
    float* out = (float*)d_out;                    // 1024 boxes + 256 scores + 256 mask

    float* f       = (float*)d_ws;                 // [256, 2048]
    float* part    = f + (size_t)NP * 2048;        // [16, 256, 200]
    float* scratch = part + (size_t)NKC * NP * HID;

    pool_kernel<<<dim3(NP, 4), 512, 0, stream>>>((const float4*)fm, coords,
                                                 (float4*)f, scratch);
    l1_kernel  <<<dim3(NP / L1_ROWS, NKC), 256, 0, stream>>>(f, W1, part);
    head_kernel<<<NP, 512, 0, stream>>>(part, b1, W2, b2, W3, b3, W4, b4,
                                        coords, out);
}